// Round 5
// baseline (277.865 us; speedup 1.0000x reference)
//
#include <hip/hip_runtime.h>
#include <hip/hip_bf16.h>

#define NN 50000
#define NE 800000
#define HF 128
#define MAXDEG 64   // Poisson(16) tail: P(deg>=64) ~ 1e-20; clamped for safety

// workspace byte offsets (256-aligned); ws_size = 256 MiB
#define OFF_FLAG   0u
#define OFF_WC1    16601088u    // 16384 bf16, FRAG-ORDER W1
#define OFF_WC2    16633856u    // 16384 bf16, FRAG-ORDER W2
#define OFF_PAR    16666624u    // 8 slots * 256 B: al1,ar1,b1,al2,ar2,b2,Wp,bp
#define OFF_Z      16668672u    // 6,400,000 bf16
#define OFF_H1     29468672u    // 6,400,000 bf16
#define OFF_EL     42268672u    // 200000 f32
#define OFF_ER     43068672u    // 200000 f32
#define OFF_FILL   54000128u    // 50000 * 4 degree counters
#define OFF_ADJ2   60000000u    // 50000 * 64 * 2 = 6.4 MB fixed-capacity adjacency (us16)

typedef __hip_bfloat16 bf16;
typedef unsigned short us16;

#define PREP_B 132       // 64 (W1) + 64 (W2) + 4 (params; 801 elems)
#define SCAT_B 3125      // NE / 256
#define SP_GRID (PREP_B + SCAT_B)
#define GEMM_B 782       // (NN + 63) / 64

typedef __attribute__((ext_vector_type(8))) short bf16x8;   // MFMA A/B frag
typedef __attribute__((ext_vector_type(4))) float f32x4;    // MFMA C/D frag

__device__ __forceinline__ float us2f(us16 u) {
  union { unsigned int i; float f; } c; c.i = ((unsigned int)u) << 16; return c.f;
}
__device__ __forceinline__ us16 f2us(float f) {
  bf16 h = __float2bfloat16(f);
  union { bf16 h; us16 u; } c; c.h = h; return c.u;
}
__device__ __forceinline__ float blo(unsigned v) {
  union { unsigned i; float f; } c; c.i = v << 16; return c.f;
}
__device__ __forceinline__ float bhi(unsigned v) {
  union { unsigned i; float f; } c; c.i = v & 0xffff0000u; return c.f;
}
__device__ __forceinline__ unsigned pk2(float a, float b) {
  return (unsigned)f2us(a) | ((unsigned)f2us(b) << 16);
}

// per-block dtype detection (W1's first 4KB, L2-broadcast)
__device__ __forceinline__ int detect_f32(const us16* __restrict__ u) {
  int t = threadIdx.x;
  int mx = 0;
  for (int i = t; i < 2048; i += 256) {
    int e = (u[i] >> 7) & 0xFF;
    mx = mx > e ? mx : e;
  }
#pragma unroll
  for (int m = 32; m >= 1; m >>= 1) {
    int o = __shfl_xor(mx, m);
    mx = mx > o ? mx : o;
  }
  __shared__ int sred[4];
  if ((t & 63) == 0) sred[t >> 6] = mx;
  __syncthreads();
  int a = sred[0] > sred[1] ? sred[0] : sred[1];
  int b = sred[2] > sred[3] ? sred[2] : sred[3];
  int r = a > b ? a : b;
  return r >= 135;
}

// ---- fused: tiny canon/permute prep (132 blocks, negligible LDS) + edge
// scatter (3125 blocks). Scatter is the memory-side atomic roofline (~47us);
// the prep blocks ride along for free instead of costing a dispatch.
// W is stored FRAG-ORDER: wc[d(k,n)] = W[k][n] with
// d = ((((k>>5)*8+(n>>4))*4+((k>>3)&3))*16+(n&15))*8+(k&7)
// so the GEMM's B-fragment load is a fully coalesced linear read (no LDS).
__global__ __launch_bounds__(256) void k_scat_prep(
    const int* __restrict__ src, const int* __restrict__ dst,
    int* __restrict__ fill, us16* __restrict__ adj2,
    const void* __restrict__ W1r, const void* __restrict__ W2r,
    const void* s2, const void* s3, const void* s4, const void* s5,
    const void* s6, const void* s7, const void* s8, const void* s9,
    us16* __restrict__ wc1, us16* __restrict__ wc2,
    us16* d2, us16* d3, us16* d4, us16* d5, us16* d6, us16* d7,
    us16* d8, us16* d9, int* __restrict__ flagp) {
  int b = (int)blockIdx.x;
  int t = threadIdx.x;
  if (b >= PREP_B) {
    int e = (b - PREP_B) * 256 + t;  // SCAT_B*256 == NE exactly
    int d = dst[e];
    int r = atomicAdd(&fill[d], 1);
    if (r < MAXDEG) adj2[(d << 6) + r] = (us16)src[e];
    return;
  }
  int f = detect_f32((const us16*)W1r);
  if (b == 0 && t == 0) *flagp = f;
  if (b < 128) {
    const void* Wr = b < 64 ? W1r : W2r;
    us16* wc = b < 64 ? wc1 : wc2;
    int e = (b & 63) * 256 + t;
    int k = e >> 7, n = e & 127;
    int d = ((((k >> 5) * 8 + (n >> 4)) * 4 + ((k >> 3) & 3)) * 16 + (n & 15)) * 8 + (k & 7);
    us16 v;
    if (f) v = f2us(((const float*)Wr)[e]);
    else v = ((const us16*)Wr)[e];
    wc[d] = v;
  } else {
    const void* sp[8] = {s2, s3, s4, s5, s6, s7, s8, s9};
    us16* dp[8] = {d2, d3, d4, d5, d6, d7, d8, d9};
    const int cnt[8] = {128, 128, 128, 128, 128, 128, 32, 1};
    int gid = (b - 128) * 256 + t;
    int base = 0;
#pragma unroll
    for (int p = 0; p < 8; ++p) {
      int loc = gid - base;
      if (loc >= 0 && loc < cnt[p]) {
        us16 v;
        if (f) v = f2us(((const float*)sp[p])[loc]);
        else v = ((const us16*)sp[p])[loc];
        dp[p][loc] = v;
      }
      base += cnt[p];
    }
  }
}

// ---- MFMA GEMM + fused el/er epilogue. NO LDS: W is pre-permuted to frag
// order, so the B-frag load Wc[((s*8+t)*64 + lane)*8] is a coalesced 1KB/wave
// read, L2-resident (32KB working set). No repack, no barrier, no detect.
// LAYER 1: X = raw feats (flag-based f32->bf16 at A-load)
// LAYER 2: X = h1 (internal bf16)
template <int LAYER>
__global__ __launch_bounds__(256) void k_gemm(
    const void* __restrict__ Xv, const us16* __restrict__ Wc,
    const us16* __restrict__ al, const us16* __restrict__ ar,
    us16* __restrict__ Z, float* __restrict__ el, float* __restrict__ er,
    const int* __restrict__ flagp) {
  int tid = threadIdx.x;
  int bx = (int)blockIdx.x;
  int w = tid >> 6;
  int lane = tid & 63;
  int q = lane >> 4;
  int c = lane & 15;
  int m0 = bx * 64 + w * 16;

  int rA = m0 + c;
  if (rA >= NN) rA = NN - 1;
  const us16* xb = (const us16*)Xv + (size_t)rA * HF;
  const float* xf = (const float*)Xv + (size_t)rA * HF;

  // preload A fragments (flag branch only on layer 1)
  bf16x8 afr[4];
  if (LAYER == 1 && *flagp) {
#pragma unroll
    for (int s = 0; s < 4; ++s) {
      float4 v0 = *(const float4*)&xf[s * 32 + q * 8];
      float4 v1 = *(const float4*)&xf[s * 32 + q * 8 + 4];
      union { us16 u[8]; bf16x8 v; } cv;
      cv.u[0] = f2us(v0.x); cv.u[1] = f2us(v0.y);
      cv.u[2] = f2us(v0.z); cv.u[3] = f2us(v0.w);
      cv.u[4] = f2us(v1.x); cv.u[5] = f2us(v1.y);
      cv.u[6] = f2us(v1.z); cv.u[7] = f2us(v1.w);
      afr[s] = cv.v;
    }
  } else {
#pragma unroll
    for (int s = 0; s < 4; ++s) afr[s] = *(const bf16x8*)&xb[s * 32 + q * 8];
  }

  f32x4 acc[8] = {};
#pragma unroll 1   // bound live B-frags (~8) to keep VGPR pressure low
  for (int s = 0; s < 4; ++s) {
#pragma unroll
    for (int t = 0; t < 8; ++t) {
      bf16x8 bb = *(const bf16x8*)&Wc[(size_t)((s * 8 + t) * 64 + lane) * 8];
      acc[t] = __builtin_amdgcn_mfma_f32_16x16x32_bf16(afr[s], bb, acc[t], 0, 0, 0);
    }
  }

#pragma unroll
  for (int reg = 0; reg < 4; ++reg) {
    int row = m0 + q * 4 + reg;
    if (row < NN) {
      us16* zrow = Z + (size_t)row * HF;
#pragma unroll
      for (int t = 0; t < 8; ++t) zrow[t * 16 + c] = f2us(acc[t][reg]);
    }
  }

  float alv[8], arv[8];
#pragma unroll
  for (int t = 0; t < 8; ++t) {
    alv[t] = us2f(al[t * 16 + c]);
    arv[t] = us2f(ar[t * 16 + c]);
  }
#pragma unroll
  for (int reg = 0; reg < 4; ++reg) {
    int row = m0 + q * 4 + reg;
    float pl[4], pr[4];
#pragma unroll
    for (int h = 0; h < 4; ++h) {
      pl[h] = acc[2 * h][reg] * alv[2 * h] + acc[2 * h + 1][reg] * alv[2 * h + 1];
      pr[h] = acc[2 * h][reg] * arv[2 * h] + acc[2 * h + 1][reg] * arv[2 * h + 1];
    }
#pragma unroll
    for (int m = 1; m < 16; m <<= 1) {
#pragma unroll
      for (int h = 0; h < 4; ++h) {
        pl[h] += __shfl_xor(pl[h], m);
        pr[h] += __shfl_xor(pr[h], m);
      }
    }
    if (row < NN) {
      int cc = c & 3;
      float vl = cc == 0 ? pl[0] : cc == 1 ? pl[1] : cc == 2 ? pl[2] : pl[3];
      float vr = cc == 0 ? pr[0] : cc == 1 ? pr[1] : cc == 2 ? pr[2] : pr[3];
      if (c < 4) el[row * 4 + cc] = vl;
      else if (c < 8) er[row * 4 + cc] = vr;
    }
  }
}

// One wave per destination node; 4 nodes per 256-thread block (no barriers).
// Adjacency row (64 us16 slots) prefetched into registers with ONE coalesced
// 128B load (lane l holds slot l); the edge loop broadcasts s via __shfl.
// Trip count is WAVE-UNIFORM so every __shfl runs with all 64 lanes active
// (ds_bpermute from an EXEC-masked lane is undefined -- the R3 bug). Invalid
// slots predicated: s clamped to 0, ex gated to 0.
template <int LAYER>
__global__ __launch_bounds__(256) void k_agg(
    const us16* __restrict__ Z, const float* __restrict__ el,
    const float* __restrict__ er, const int* __restrict__ fill,
    const us16* __restrict__ adj2, const void* __restrict__ resid,
    const us16* __restrict__ bias, us16* __restrict__ Hout,
    const us16* __restrict__ Wp, const us16* __restrict__ bp,
    void* __restrict__ out, const int* __restrict__ flag) {
  int f = *flag;
  int n = blockIdx.x * 4 + (threadIdx.x >> 6);
  int lane = threadIdx.x & 63;
  int g = lane >> 4;
  int p = lane & 15;
  int hl = p >> 2;
  int f0 = p * 8;
  int begin = n << 6;

  int sl = (int)adj2[begin + lane];  // register-resident adjacency row

  int deg = fill[n];
  if (deg > MAXDEG) deg = MAXDEG;
  float erh = er[n * 4 + hl];

  float acc[8] = {};
  float ssum = 0.f;
  for (int k = 0; k * 8 < deg; ++k) {  // uniform trip count across the wave
    int i0 = g + k * 8;
    int i1 = i0 + 4;
    int s0 = __shfl(sl, i0);           // all 64 lanes active
    int s1 = __shfl(sl, i1);
    bool v0 = i0 < deg;
    bool v1 = i1 < deg;
    s0 = v0 ? s0 : 0;
    s1 = v1 ? s1 : 0;
    float l0 = el[s0 * 4 + hl];
    float l1 = el[s1 * 4 + hl];
    uint4 za = *(const uint4*)&Z[(size_t)s0 * HF + f0];
    uint4 zb = *(const uint4*)&Z[(size_t)s1 * HF + f0];
    float sc0 = l0 + erh; sc0 = sc0 > 0.f ? sc0 : 0.2f * sc0;
    float sc1 = l1 + erh; sc1 = sc1 > 0.f ? sc1 : 0.2f * sc1;
    float ex0 = v0 ? __expf(sc0) : 0.f;
    float ex1 = v1 ? __expf(sc1) : 0.f;
    ssum += ex0 + ex1;
    acc[0] = fmaf(ex0, blo(za.x), acc[0]); acc[1] = fmaf(ex0, bhi(za.x), acc[1]);
    acc[2] = fmaf(ex0, blo(za.y), acc[2]); acc[3] = fmaf(ex0, bhi(za.y), acc[3]);
    acc[4] = fmaf(ex0, blo(za.z), acc[4]); acc[5] = fmaf(ex0, bhi(za.z), acc[5]);
    acc[6] = fmaf(ex0, blo(za.w), acc[6]); acc[7] = fmaf(ex0, bhi(za.w), acc[7]);
    acc[0] = fmaf(ex1, blo(zb.x), acc[0]); acc[1] = fmaf(ex1, bhi(zb.x), acc[1]);
    acc[2] = fmaf(ex1, blo(zb.y), acc[2]); acc[3] = fmaf(ex1, bhi(zb.y), acc[3]);
    acc[4] = fmaf(ex1, blo(zb.z), acc[4]); acc[5] = fmaf(ex1, bhi(zb.z), acc[5]);
    acc[6] = fmaf(ex1, blo(zb.w), acc[6]); acc[7] = fmaf(ex1, bhi(zb.w), acc[7]);
  }
  ssum += __shfl_xor(ssum, 16); ssum += __shfl_xor(ssum, 32);
#pragma unroll
  for (int j = 0; j < 8; ++j) {
    acc[j] += __shfl_xor(acc[j], 16);
    acc[j] += __shfl_xor(acc[j], 32);
  }
  float inv = 1.f / fmaxf(ssum, 1e-9f);

  float rx[8];
  if (LAYER == 1 && f) {
    const float* rf = (const float*)resid + (size_t)n * HF + f0;
    float4 r0 = *(const float4*)rf;
    float4 r1 = *(const float4*)(rf + 4);
    rx[0] = r0.x; rx[1] = r0.y; rx[2] = r0.z; rx[3] = r0.w;
    rx[4] = r1.x; rx[5] = r1.y; rx[6] = r1.z; rx[7] = r1.w;
  } else {
    uint4 xq = *(const uint4*)((const us16*)resid + (size_t)n * HF + f0);
    rx[0] = blo(xq.x); rx[1] = bhi(xq.x); rx[2] = blo(xq.y); rx[3] = bhi(xq.y);
    rx[4] = blo(xq.z); rx[5] = bhi(xq.z); rx[6] = blo(xq.w); rx[7] = bhi(xq.w);
  }
  uint4 bq = *(const uint4*)&bias[f0];
  float t0 = fmaf(acc[0], inv, rx[0] + blo(bq.x));
  float t1 = fmaf(acc[1], inv, rx[1] + bhi(bq.x));
  float t2 = fmaf(acc[2], inv, rx[2] + blo(bq.y));
  float t3 = fmaf(acc[3], inv, rx[3] + bhi(bq.y));
  float t4 = fmaf(acc[4], inv, rx[4] + blo(bq.z));
  float t5 = fmaf(acc[5], inv, rx[5] + bhi(bq.z));
  float t6 = fmaf(acc[6], inv, rx[6] + blo(bq.w));
  float t7 = fmaf(acc[7], inv, rx[7] + bhi(bq.w));

  if (LAYER == 1) {
    t0 = t0 > 0.f ? t0 : __expf(t0) - 1.f;
    t1 = t1 > 0.f ? t1 : __expf(t1) - 1.f;
    t2 = t2 > 0.f ? t2 : __expf(t2) - 1.f;
    t3 = t3 > 0.f ? t3 : __expf(t3) - 1.f;
    t4 = t4 > 0.f ? t4 : __expf(t4) - 1.f;
    t5 = t5 > 0.f ? t5 : __expf(t5) - 1.f;
    t6 = t6 > 0.f ? t6 : __expf(t6) - 1.f;
    t7 = t7 > 0.f ? t7 : __expf(t7) - 1.f;
    if (g == 0) {
      uint4 o;
      o.x = pk2(t0, t1); o.y = pk2(t2, t3); o.z = pk2(t4, t5); o.w = pk2(t6, t7);
      *(uint4*)&Hout[(size_t)n * HF + f0] = o;
    }
  } else {
    t0 += __shfl_xor(t0, 4); t0 += __shfl_xor(t0, 8);
    t1 += __shfl_xor(t1, 4); t1 += __shfl_xor(t1, 8);
    t2 += __shfl_xor(t2, 4); t2 += __shfl_xor(t2, 8);
    t3 += __shfl_xor(t3, 4); t3 += __shfl_xor(t3, 8);
    t4 += __shfl_xor(t4, 4); t4 += __shfl_xor(t4, 8);
    t5 += __shfl_xor(t5, 4); t5 += __shfl_xor(t5, 8);
    t6 += __shfl_xor(t6, 4); t6 += __shfl_xor(t6, 8);
    t7 += __shfl_xor(t7, 4); t7 += __shfl_xor(t7, 8);
    int fw = (p & 3) * 8;
    float pr = 0.25f * (t0 * us2f(Wp[fw]) + t1 * us2f(Wp[fw + 1]) +
                        t2 * us2f(Wp[fw + 2]) + t3 * us2f(Wp[fw + 3]) +
                        t4 * us2f(Wp[fw + 4]) + t5 * us2f(Wp[fw + 5]) +
                        t6 * us2f(Wp[fw + 6]) + t7 * us2f(Wp[fw + 7]));
    pr += __shfl_xor(pr, 1); pr += __shfl_xor(pr, 2);
    if (lane == 0) {
      float res = pr + us2f(bp[0]);
      if (f) ((float*)out)[n] = res;
      else ((us16*)out)[n] = f2us(res);
    }
  }
}

extern "C" void kernel_launch(void* const* d_in, const int* in_sizes, int n_in,
                              void* d_out, int out_size, void* d_ws, size_t ws_size,
                              hipStream_t stream) {
  const int* src = (const int*)d_in[1];
  const int* dst = (const int*)d_in[2];
  char* ws = (char*)d_ws;
  int* flag   = (int*)(ws + OFF_FLAG);
  us16* wc1   = (us16*)(ws + OFF_WC1);
  us16* wc2   = (us16*)(ws + OFF_WC2);
  us16* al1   = (us16*)(ws + OFF_PAR + 0);
  us16* ar1   = (us16*)(ws + OFF_PAR + 256);
  us16* b1    = (us16*)(ws + OFF_PAR + 512);
  us16* al2   = (us16*)(ws + OFF_PAR + 768);
  us16* ar2   = (us16*)(ws + OFF_PAR + 1024);
  us16* b2    = (us16*)(ws + OFF_PAR + 1280);
  us16* wp    = (us16*)(ws + OFF_PAR + 1536);
  us16* bp    = (us16*)(ws + OFF_PAR + 1792);
  us16* z     = (us16*)(ws + OFF_Z);
  us16* h1    = (us16*)(ws + OFF_H1);
  float* el   = (float*)(ws + OFF_EL);
  float* er   = (float*)(ws + OFF_ER);
  int* fill   = (int*)(ws + OFF_FILL);
  us16* adj2  = (us16*)(ws + OFF_ADJ2);

  hipMemsetAsync(fill, 0, (size_t)NN * 4, stream);  // zero degree counters

  // 1) fused scatter (atomic roofline) + tiny canon/frag-permute prep
  hipLaunchKernelGGL(k_scat_prep, dim3(SP_GRID), dim3(256), 0, stream,
                     src, dst, fill, adj2,
                     d_in[3], d_in[7], d_in[4], d_in[5], d_in[6],
                     d_in[8], d_in[9], d_in[10], d_in[11], d_in[12],
                     wc1, wc2, al1, ar1, b1, al2, ar2, b2, wp, bp, flag);
  // 2) layer-1 gemm (LDS-free, frag-order W; raw feats A-path)
  hipLaunchKernelGGL((k_gemm<1>), dim3(GEMM_B), dim3(256), 0, stream,
                     d_in[0], wc1, al1, ar1, z, el, er, flag);
  // 3) layer-1 aggregation (residual+bias+ELU fused; raw feats residual)
  hipLaunchKernelGGL((k_agg<1>), dim3(NN / 4), dim3(256), 0, stream, z, el, er,
                     fill, adj2, d_in[0], b1, h1,
                     (const us16*)nullptr, (const us16*)nullptr, (void*)nullptr, flag);
  // 4) layer-2 gemm
  hipLaunchKernelGGL((k_gemm<2>), dim3(GEMM_B), dim3(256), 0, stream,
                     h1, wc2, al2, ar2, z, el, er, flag);
  // 5) layer-2 aggregation (+ head-mean + projection + bp)
  hipLaunchKernelGGL((k_agg<2>), dim3(NN / 4), dim3(256), 0, stream, z, el, er,
                     fill, adj2, h1, b2, (us16*)nullptr,
                     wp, bp, d_out, flag);
}

// Round 6
// 265.797 us; speedup vs baseline: 1.0454x; 1.0454x over previous
//
#include <hip/hip_runtime.h>
#include <hip/hip_bf16.h>

#define NN 50000
#define NE 800000
#define HF 128
#define MAXDEG 64   // Poisson(16) tail: P(deg>=64) ~ 1e-20; clamped for safety

// workspace byte offsets (256-aligned); ws_size = 256 MiB
#define OFF_FLAG   0u
#define OFF_WC1    16601088u    // 16384 bf16, FRAG-ORDER W1
#define OFF_WC2    16633856u    // 16384 bf16, FRAG-ORDER W2
#define OFF_PAR    16666624u    // 8 slots * 256 B: al1,ar1,b1,al2,ar2,b2,Wp,bp
#define OFF_Z      16668672u    // 6,400,000 bf16
#define OFF_H1     29468672u    // 6,400,000 bf16
#define OFF_EL     42268672u    // 200000 f32
#define OFF_ER     43068672u    // 200000 f32
#define OFF_FILL   54000128u    // 50000 * 4 degree counters
#define OFF_ADJ2   60000000u    // 50000 * 64 * 2 = 6.4 MB fixed-capacity adjacency (us16)

typedef __hip_bfloat16 bf16;
typedef unsigned short us16;

#define PREP_B 132       // 64 (W1) + 64 (W2) + 4 (params; 801 elems); also zeroes fill
#define SCAT_B 3125      // NE / 256
#define GEMM_B 782       // (NN + 63) / 64

typedef __attribute__((ext_vector_type(8))) short bf16x8;   // MFMA A/B frag
typedef __attribute__((ext_vector_type(4))) float f32x4;    // MFMA C/D frag
typedef __attribute__((ext_vector_type(4))) unsigned int u32x4;

__device__ __forceinline__ float us2f(us16 u) {
  union { unsigned int i; float f; } c; c.i = ((unsigned int)u) << 16; return c.f;
}
__device__ __forceinline__ us16 f2us(float f) {
  bf16 h = __float2bfloat16(f);
  union { bf16 h; us16 u; } c; c.h = h; return c.u;
}
__device__ __forceinline__ float blo(unsigned v) {
  union { unsigned i; float f; } c; c.i = v << 16; return c.f;
}
__device__ __forceinline__ float bhi(unsigned v) {
  union { unsigned i; float f; } c; c.i = v & 0xffff0000u; return c.f;
}
__device__ __forceinline__ unsigned pk2(float a, float b) {
  return (unsigned)f2us(a) | ((unsigned)f2us(b) << 16);
}

// per-block dtype detection (W1's first 4KB, L2-broadcast)
__device__ __forceinline__ int detect_f32(const us16* __restrict__ u) {
  int t = threadIdx.x;
  int mx = 0;
  for (int i = t; i < 2048; i += 256) {
    int e = (u[i] >> 7) & 0xFF;
    mx = mx > e ? mx : e;
  }
#pragma unroll
  for (int m = 32; m >= 1; m >>= 1) {
    int o = __shfl_xor(mx, m);
    mx = mx > o ? mx : o;
  }
  __shared__ int sred[4];
  if ((t & 63) == 0) sred[t >> 6] = mx;
  __syncthreads();
  int a = sred[0] > sred[1] ? sred[0] : sred[1];
  int b = sred[2] > sred[3] ? sred[2] : sred[3];
  int r = a > b ? a : b;
  return r >= 135;
}

// ---- tiny prep: W frag-order permute + param canon + fill zeroing.
// Dedicated dispatch (fusing it into the scatter cost ~10us of atomic
// throughput in R5); also replaces the hipMemsetAsync(fill) dispatch.
__global__ __launch_bounds__(256) void k_prep(
    const void* __restrict__ W1r, const void* __restrict__ W2r,
    const void* s2, const void* s3, const void* s4, const void* s5,
    const void* s6, const void* s7, const void* s8, const void* s9,
    us16* __restrict__ wc1, us16* __restrict__ wc2,
    us16* d2, us16* d3, us16* d4, us16* d5, us16* d6, us16* d7,
    us16* d8, us16* d9, int* __restrict__ fill, int* __restrict__ flagp) {
  int b = (int)blockIdx.x;
  int t = threadIdx.x;
  // zero degree counters (grid-stride over NN)
  for (int i = b * 256 + t; i < NN; i += PREP_B * 256) fill[i] = 0;
  int f = detect_f32((const us16*)W1r);
  if (b == 0 && t == 0) *flagp = f;
  if (b < 128) {
    const void* Wr = b < 64 ? W1r : W2r;
    us16* wc = b < 64 ? wc1 : wc2;
    int e = (b & 63) * 256 + t;
    int k = e >> 7, n = e & 127;
    int d = ((((k >> 5) * 8 + (n >> 4)) * 4 + ((k >> 3) & 3)) * 16 + (n & 15)) * 8 + (k & 7);
    us16 v;
    if (f) v = f2us(((const float*)Wr)[e]);
    else v = ((const us16*)Wr)[e];
    wc[d] = v;
  } else {
    const void* sp[8] = {s2, s3, s4, s5, s6, s7, s8, s9};
    us16* dp[8] = {d2, d3, d4, d5, d6, d7, d8, d9};
    const int cnt[8] = {128, 128, 128, 128, 128, 128, 32, 1};
    int gid = (b - 128) * 256 + t;
    int base = 0;
#pragma unroll
    for (int p = 0; p < 8; ++p) {
      int loc = gid - base;
      if (loc >= 0 && loc < cnt[p]) {
        us16 v;
        if (f) v = f2us(((const float*)sp[p])[loc]);
        else v = ((const us16*)sp[p])[loc];
        dp[p][loc] = v;
      }
      base += cnt[p];
    }
  }
}

// ---- dedicated edge scatter: 1 edge/thread (R4-proven ~47us; fusing anything
// into this kernel regressed it twice). Memory-side atomic service is the
// roofline; high wave count pipelines adj2 stores under later waves' atomics.
__global__ __launch_bounds__(256) void k_scatter(
    const int* __restrict__ src, const int* __restrict__ dst,
    int* __restrict__ fill, us16* __restrict__ adj2) {
  int e = blockIdx.x * 256 + threadIdx.x;  // SCAT_B*256 == NE exactly
  int d = dst[e];
  int r = atomicAdd(&fill[d], 1);
  if (r < MAXDEG) adj2[(d << 6) + r] = (us16)src[e];
}

// ---- MFMA GEMM + fused el/er epilogue. NO LDS: W pre-permuted to frag order,
// B-frag load is a coalesced linear read (L2-resident 32KB). All output
// streams (Z, el, er) use NONTEMPORAL stores: they are partial-line writes,
// and normal stores trigger L2 write-allocate (R4 counter evidence: gemm
// FETCH_SIZE == 12.8MB == sizeof(Z), pure RMW overhead) plus cross-XCD
// dirty-line bounce for the consumer kernel.
template <int LAYER>
__global__ __launch_bounds__(256) void k_gemm(
    const void* __restrict__ Xv, const us16* __restrict__ Wc,
    const us16* __restrict__ al, const us16* __restrict__ ar,
    us16* __restrict__ Z, float* __restrict__ el, float* __restrict__ er,
    const int* __restrict__ flagp) {
  int tid = threadIdx.x;
  int bx = (int)blockIdx.x;
  int w = tid >> 6;
  int lane = tid & 63;
  int q = lane >> 4;
  int c = lane & 15;
  int m0 = bx * 64 + w * 16;

  int rA = m0 + c;
  if (rA >= NN) rA = NN - 1;
  const us16* xb = (const us16*)Xv + (size_t)rA * HF;
  const float* xf = (const float*)Xv + (size_t)rA * HF;

  bf16x8 afr[4];
  if (LAYER == 1 && *flagp) {
#pragma unroll
    for (int s = 0; s < 4; ++s) {
      float4 v0 = *(const float4*)&xf[s * 32 + q * 8];
      float4 v1 = *(const float4*)&xf[s * 32 + q * 8 + 4];
      union { us16 u[8]; bf16x8 v; } cv;
      cv.u[0] = f2us(v0.x); cv.u[1] = f2us(v0.y);
      cv.u[2] = f2us(v0.z); cv.u[3] = f2us(v0.w);
      cv.u[4] = f2us(v1.x); cv.u[5] = f2us(v1.y);
      cv.u[6] = f2us(v1.z); cv.u[7] = f2us(v1.w);
      afr[s] = cv.v;
    }
  } else {
#pragma unroll
    for (int s = 0; s < 4; ++s) afr[s] = *(const bf16x8*)&xb[s * 32 + q * 8];
  }

  f32x4 acc[8] = {};
#pragma unroll 1   // bound live B-frags to keep VGPR pressure low
  for (int s = 0; s < 4; ++s) {
#pragma unroll
    for (int t = 0; t < 8; ++t) {
      bf16x8 bb = *(const bf16x8*)&Wc[(size_t)((s * 8 + t) * 64 + lane) * 8];
      acc[t] = __builtin_amdgcn_mfma_f32_16x16x32_bf16(afr[s], bb, acc[t], 0, 0, 0);
    }
  }

#pragma unroll
  for (int reg = 0; reg < 4; ++reg) {
    int row = m0 + q * 4 + reg;
    if (row < NN) {
      us16* zrow = Z + (size_t)row * HF;
#pragma unroll
      for (int t = 0; t < 8; ++t)
        __builtin_nontemporal_store(f2us(acc[t][reg]), &zrow[t * 16 + c]);
    }
  }

  float alv[8], arv[8];
#pragma unroll
  for (int t = 0; t < 8; ++t) {
    alv[t] = us2f(al[t * 16 + c]);
    arv[t] = us2f(ar[t * 16 + c]);
  }
#pragma unroll
  for (int reg = 0; reg < 4; ++reg) {
    int row = m0 + q * 4 + reg;
    float pl[4], pr[4];
#pragma unroll
    for (int h = 0; h < 4; ++h) {
      pl[h] = acc[2 * h][reg] * alv[2 * h] + acc[2 * h + 1][reg] * alv[2 * h + 1];
      pr[h] = acc[2 * h][reg] * arv[2 * h] + acc[2 * h + 1][reg] * arv[2 * h + 1];
    }
#pragma unroll
    for (int m = 1; m < 16; m <<= 1) {
#pragma unroll
      for (int h = 0; h < 4; ++h) {
        pl[h] += __shfl_xor(pl[h], m);
        pr[h] += __shfl_xor(pr[h], m);
      }
    }
    if (row < NN) {
      int cc = c & 3;
      float vl = cc == 0 ? pl[0] : cc == 1 ? pl[1] : cc == 2 ? pl[2] : pl[3];
      float vr = cc == 0 ? pr[0] : cc == 1 ? pr[1] : cc == 2 ? pr[2] : pr[3];
      if (c < 4) __builtin_nontemporal_store(vl, &el[row * 4 + cc]);
      else if (c < 8) __builtin_nontemporal_store(vr, &er[row * 4 + cc]);
    }
  }
}

// One wave per destination node; 4 nodes per 256-thread block (no barriers).
// Register-resident adjacency row + __shfl broadcast (R4-proven). Edge loop
// unrolled 4-wide per group (16 edges/iter per wave) for deeper MLP: 4
// independent Z-row loads in flight instead of 2. Trip count is WAVE-UNIFORM
// so every __shfl runs all-lanes-active (the R3 bug); invalid slots
// predicated (s->0, ex->0). Outputs (Hout/out) use NT stores.
template <int LAYER>
__global__ __launch_bounds__(256) void k_agg(
    const us16* __restrict__ Z, const float* __restrict__ el,
    const float* __restrict__ er, const int* __restrict__ fill,
    const us16* __restrict__ adj2, const void* __restrict__ resid,
    const us16* __restrict__ bias, us16* __restrict__ Hout,
    const us16* __restrict__ Wp, const us16* __restrict__ bp,
    void* __restrict__ out, const int* __restrict__ flag) {
  int f = *flag;
  int n = blockIdx.x * 4 + (threadIdx.x >> 6);
  int lane = threadIdx.x & 63;
  int g = lane >> 4;
  int p = lane & 15;
  int hl = p >> 2;
  int f0 = p * 8;
  int begin = n << 6;

  int sl = (int)adj2[begin + lane];  // register-resident adjacency row

  int deg = fill[n];
  if (deg > MAXDEG) deg = MAXDEG;
  float erh = er[n * 4 + hl];

  float acc[8] = {};
  float ssum = 0.f;
  for (int k = 0; k * 16 < deg; ++k) {  // uniform trip count across the wave
    int ib = g + k * 16;
    int i0 = ib, i1 = ib + 4, i2 = ib + 8, i3 = ib + 12;  // i3 <= 63
    int s0 = __shfl(sl, i0);            // all 64 lanes active
    int s1 = __shfl(sl, i1);
    int s2 = __shfl(sl, i2);
    int s3 = __shfl(sl, i3);
    bool v0 = i0 < deg, v1 = i1 < deg, v2 = i2 < deg, v3 = i3 < deg;
    s0 = v0 ? s0 : 0; s1 = v1 ? s1 : 0; s2 = v2 ? s2 : 0; s3 = v3 ? s3 : 0;
    float l0 = el[s0 * 4 + hl];
    float l1 = el[s1 * 4 + hl];
    float l2 = el[s2 * 4 + hl];
    float l3 = el[s3 * 4 + hl];
    uint4 za = *(const uint4*)&Z[(size_t)s0 * HF + f0];
    uint4 zb = *(const uint4*)&Z[(size_t)s1 * HF + f0];
    uint4 zc = *(const uint4*)&Z[(size_t)s2 * HF + f0];
    uint4 zd = *(const uint4*)&Z[(size_t)s3 * HF + f0];
    float sc0 = l0 + erh; sc0 = sc0 > 0.f ? sc0 : 0.2f * sc0;
    float sc1 = l1 + erh; sc1 = sc1 > 0.f ? sc1 : 0.2f * sc1;
    float sc2 = l2 + erh; sc2 = sc2 > 0.f ? sc2 : 0.2f * sc2;
    float sc3 = l3 + erh; sc3 = sc3 > 0.f ? sc3 : 0.2f * sc3;
    float ex0 = v0 ? __expf(sc0) : 0.f;
    float ex1 = v1 ? __expf(sc1) : 0.f;
    float ex2 = v2 ? __expf(sc2) : 0.f;
    float ex3 = v3 ? __expf(sc3) : 0.f;
    ssum += (ex0 + ex1) + (ex2 + ex3);
    acc[0] = fmaf(ex0, blo(za.x), acc[0]); acc[1] = fmaf(ex0, bhi(za.x), acc[1]);
    acc[2] = fmaf(ex0, blo(za.y), acc[2]); acc[3] = fmaf(ex0, bhi(za.y), acc[3]);
    acc[4] = fmaf(ex0, blo(za.z), acc[4]); acc[5] = fmaf(ex0, bhi(za.z), acc[5]);
    acc[6] = fmaf(ex0, blo(za.w), acc[6]); acc[7] = fmaf(ex0, bhi(za.w), acc[7]);
    acc[0] = fmaf(ex1, blo(zb.x), acc[0]); acc[1] = fmaf(ex1, bhi(zb.x), acc[1]);
    acc[2] = fmaf(ex1, blo(zb.y), acc[2]); acc[3] = fmaf(ex1, bhi(zb.y), acc[3]);
    acc[4] = fmaf(ex1, blo(zb.z), acc[4]); acc[5] = fmaf(ex1, bhi(zb.z), acc[5]);
    acc[6] = fmaf(ex1, blo(zb.w), acc[6]); acc[7] = fmaf(ex1, bhi(zb.w), acc[7]);
    acc[0] = fmaf(ex2, blo(zc.x), acc[0]); acc[1] = fmaf(ex2, bhi(zc.x), acc[1]);
    acc[2] = fmaf(ex2, blo(zc.y), acc[2]); acc[3] = fmaf(ex2, bhi(zc.y), acc[3]);
    acc[4] = fmaf(ex2, blo(zc.z), acc[4]); acc[5] = fmaf(ex2, bhi(zc.z), acc[5]);
    acc[6] = fmaf(ex2, blo(zc.w), acc[6]); acc[7] = fmaf(ex2, bhi(zc.w), acc[7]);
    acc[0] = fmaf(ex3, blo(zd.x), acc[0]); acc[1] = fmaf(ex3, bhi(zd.x), acc[1]);
    acc[2] = fmaf(ex3, blo(zd.y), acc[2]); acc[3] = fmaf(ex3, bhi(zd.y), acc[3]);
    acc[4] = fmaf(ex3, blo(zd.z), acc[4]); acc[5] = fmaf(ex3, bhi(zd.z), acc[5]);
    acc[6] = fmaf(ex3, blo(zd.w), acc[6]); acc[7] = fmaf(ex3, bhi(zd.w), acc[7]);
  }
  ssum += __shfl_xor(ssum, 16); ssum += __shfl_xor(ssum, 32);
#pragma unroll
  for (int j = 0; j < 8; ++j) {
    acc[j] += __shfl_xor(acc[j], 16);
    acc[j] += __shfl_xor(acc[j], 32);
  }
  float inv = 1.f / fmaxf(ssum, 1e-9f);

  float rx[8];
  if (LAYER == 1 && f) {
    const float* rf = (const float*)resid + (size_t)n * HF + f0;
    float4 r0 = *(const float4*)rf;
    float4 r1 = *(const float4*)(rf + 4);
    rx[0] = r0.x; rx[1] = r0.y; rx[2] = r0.z; rx[3] = r0.w;
    rx[4] = r1.x; rx[5] = r1.y; rx[6] = r1.z; rx[7] = r1.w;
  } else {
    uint4 xq = *(const uint4*)((const us16*)resid + (size_t)n * HF + f0);
    rx[0] = blo(xq.x); rx[1] = bhi(xq.x); rx[2] = blo(xq.y); rx[3] = bhi(xq.y);
    rx[4] = blo(xq.z); rx[5] = bhi(xq.z); rx[6] = blo(xq.w); rx[7] = bhi(xq.w);
  }
  uint4 bq = *(const uint4*)&bias[f0];
  float t0 = fmaf(acc[0], inv, rx[0] + blo(bq.x));
  float t1 = fmaf(acc[1], inv, rx[1] + bhi(bq.x));
  float t2 = fmaf(acc[2], inv, rx[2] + blo(bq.y));
  float t3 = fmaf(acc[3], inv, rx[3] + bhi(bq.y));
  float t4 = fmaf(acc[4], inv, rx[4] + blo(bq.z));
  float t5 = fmaf(acc[5], inv, rx[5] + bhi(bq.z));
  float t6 = fmaf(acc[6], inv, rx[6] + blo(bq.w));
  float t7 = fmaf(acc[7], inv, rx[7] + bhi(bq.w));

  if (LAYER == 1) {
    t0 = t0 > 0.f ? t0 : __expf(t0) - 1.f;
    t1 = t1 > 0.f ? t1 : __expf(t1) - 1.f;
    t2 = t2 > 0.f ? t2 : __expf(t2) - 1.f;
    t3 = t3 > 0.f ? t3 : __expf(t3) - 1.f;
    t4 = t4 > 0.f ? t4 : __expf(t4) - 1.f;
    t5 = t5 > 0.f ? t5 : __expf(t5) - 1.f;
    t6 = t6 > 0.f ? t6 : __expf(t6) - 1.f;
    t7 = t7 > 0.f ? t7 : __expf(t7) - 1.f;
    if (g == 0) {
      u32x4 o;
      o.x = pk2(t0, t1); o.y = pk2(t2, t3); o.z = pk2(t4, t5); o.w = pk2(t6, t7);
      __builtin_nontemporal_store(o, (u32x4*)&Hout[(size_t)n * HF + f0]);
    }
  } else {
    t0 += __shfl_xor(t0, 4); t0 += __shfl_xor(t0, 8);
    t1 += __shfl_xor(t1, 4); t1 += __shfl_xor(t1, 8);
    t2 += __shfl_xor(t2, 4); t2 += __shfl_xor(t2, 8);
    t3 += __shfl_xor(t3, 4); t3 += __shfl_xor(t3, 8);
    t4 += __shfl_xor(t4, 4); t4 += __shfl_xor(t4, 8);
    t5 += __shfl_xor(t5, 4); t5 += __shfl_xor(t5, 8);
    t6 += __shfl_xor(t6, 4); t6 += __shfl_xor(t6, 8);
    t7 += __shfl_xor(t7, 4); t7 += __shfl_xor(t7, 8);
    int fw = (p & 3) * 8;
    float pr = 0.25f * (t0 * us2f(Wp[fw]) + t1 * us2f(Wp[fw + 1]) +
                        t2 * us2f(Wp[fw + 2]) + t3 * us2f(Wp[fw + 3]) +
                        t4 * us2f(Wp[fw + 4]) + t5 * us2f(Wp[fw + 5]) +
                        t6 * us2f(Wp[fw + 6]) + t7 * us2f(Wp[fw + 7]));
    pr += __shfl_xor(pr, 1); pr += __shfl_xor(pr, 2);
    if (lane == 0) {
      float res = pr + us2f(bp[0]);
      if (f) __builtin_nontemporal_store(res, &((float*)out)[n]);
      else __builtin_nontemporal_store(f2us(res), &((us16*)out)[n]);
    }
  }
}

extern "C" void kernel_launch(void* const* d_in, const int* in_sizes, int n_in,
                              void* d_out, int out_size, void* d_ws, size_t ws_size,
                              hipStream_t stream) {
  const int* src = (const int*)d_in[1];
  const int* dst = (const int*)d_in[2];
  char* ws = (char*)d_ws;
  int* flag   = (int*)(ws + OFF_FLAG);
  us16* wc1   = (us16*)(ws + OFF_WC1);
  us16* wc2   = (us16*)(ws + OFF_WC2);
  us16* al1   = (us16*)(ws + OFF_PAR + 0);
  us16* ar1   = (us16*)(ws + OFF_PAR + 256);
  us16* b1    = (us16*)(ws + OFF_PAR + 512);
  us16* al2   = (us16*)(ws + OFF_PAR + 768);
  us16* ar2   = (us16*)(ws + OFF_PAR + 1024);
  us16* b2    = (us16*)(ws + OFF_PAR + 1280);
  us16* wp    = (us16*)(ws + OFF_PAR + 1536);
  us16* bp    = (us16*)(ws + OFF_PAR + 1792);
  us16* z     = (us16*)(ws + OFF_Z);
  us16* h1    = (us16*)(ws + OFF_H1);
  float* el   = (float*)(ws + OFF_EL);
  float* er   = (float*)(ws + OFF_ER);
  int* fill   = (int*)(ws + OFF_FILL);
  us16* adj2  = (us16*)(ws + OFF_ADJ2);

  // 1) tiny prep: W permute + param canon + fill zeroing (replaces memset)
  hipLaunchKernelGGL(k_prep, dim3(PREP_B), dim3(256), 0, stream,
                     d_in[3], d_in[7], d_in[4], d_in[5], d_in[6],
                     d_in[8], d_in[9], d_in[10], d_in[11], d_in[12],
                     wc1, wc2, al1, ar1, b1, al2, ar2, b2, wp, bp, fill, flag);
  // 2) dedicated edge scatter (atomic roofline; R4-proven)
  hipLaunchKernelGGL(k_scatter, dim3(SCAT_B), dim3(256), 0, stream,
                     src, dst, fill, adj2);
  // 3) layer-1 gemm (LDS-free, NT output streams)
  hipLaunchKernelGGL((k_gemm<1>), dim3(GEMM_B), dim3(256), 0, stream,
                     d_in[0], wc1, al1, ar1, z, el, er, flag);
  // 4) layer-1 aggregation (residual+bias+ELU fused; 4-wide edge unroll)
  hipLaunchKernelGGL((k_agg<1>), dim3(NN / 4), dim3(256), 0, stream, z, el, er,
                     fill, adj2, d_in[0], b1, h1,
                     (const us16*)nullptr, (const us16*)nullptr, (void*)nullptr, flag);
  // 5) layer-2 gemm
  hipLaunchKernelGGL((k_gemm<2>), dim3(GEMM_B), dim3(256), 0, stream,
                     h1, wc2, al2, ar2, z, el, er, flag);
  // 6) layer-2 aggregation (+ head-mean + projection + bp)
  hipLaunchKernelGGL((k_agg<2>), dim3(NN / 4), dim3(256), 0, stream, z, el, er,
                     fill, adj2, h1, b2, (us16*)nullptr,
                     wp, bp, d_out, flag);
}